// Round 1
// baseline (1597.314 us; speedup 1.0000x reference)
//
#include <hip/hip_runtime.h>
#include <hip/hip_bf16.h>
#include <math.h>

#define THREADS 256

__global__ void zero_i32(int* __restrict__ p, int n) {
    int i = blockIdx.x * blockDim.x + threadIdx.x;
    if (i < n) p[i] = 0;
}

__global__ void count_kernel(const int* __restrict__ dst, int* __restrict__ cnt, int E) {
    int e = blockIdx.x * blockDim.x + threadIdx.x;
    if (e < E) atomicAdd(&cnt[dst[e]], 1);
}

__global__ void dinv_kernel(const int* __restrict__ cnt, float* __restrict__ dinv, int n) {
    int i = blockIdx.x * blockDim.x + threadIdx.x;
    if (i < n) dinv[i] = rsqrtf((float)cnt[i] + 1.0f);
}

// single-block exclusive scan over cnt -> rowptr[0..n], also copies to cursor
__global__ void scan_kernel(const int* __restrict__ cnt, int* __restrict__ rowptr,
                            int* __restrict__ cursor, int n) {
    __shared__ int smem[1024];
    __shared__ int s_running;
    if (threadIdx.x == 0) s_running = 0;
    __syncthreads();
    for (int base = 0; base < n; base += 1024) {
        int i = base + threadIdx.x;
        int v = (i < n) ? cnt[i] : 0;
        smem[threadIdx.x] = v;
        __syncthreads();
        int acc = v;
        for (int off = 1; off < 1024; off <<= 1) {
            int t = (threadIdx.x >= off) ? smem[threadIdx.x - off] : 0;
            __syncthreads();
            acc += t;
            smem[threadIdx.x] = acc;
            __syncthreads();
        }
        int run = s_running;                 // uniform read
        int excl = run + acc - v;
        if (i < n) { rowptr[i] = excl; cursor[i] = excl; }
        __syncthreads();
        if (threadIdx.x == 0) s_running = run + smem[1023];
        __syncthreads();
    }
    if (threadIdx.x == 0) rowptr[n] = s_running;
}

__global__ void scatter_kernel(const int* __restrict__ src, const int* __restrict__ dst,
                               int* __restrict__ cursor, int* __restrict__ col, int E) {
    int e = blockIdx.x * blockDim.x + threadIdx.x;
    if (e < E) {
        int d = dst[e];
        int p = atomicAdd(&cursor[d], 1);
        col[p] = src[e];
    }
}

// Y[i,j] = (sum_k X[i,k] * W[k,j]) * dinv[i]   -- pre-scaled for aggregation
template<int FIN, int FOUT>
__global__ void mm_scale_kernel(const float* __restrict__ X, const float* __restrict__ W,
                                const float* __restrict__ dinv, float* __restrict__ Y, int n) {
    __shared__ float sW[FIN * FOUT];
    for (int idx = threadIdx.x; idx < FIN * FOUT; idx += blockDim.x) sW[idx] = W[idx];
    __syncthreads();
    int tid = blockIdx.x * blockDim.x + threadIdx.x;
    if (tid >= n * FOUT) return;
    int i = tid / FOUT;
    int j = tid - i * FOUT;
    const float* xr = X + (size_t)i * FIN;
    float acc = 0.f;
#pragma unroll
    for (int k = 0; k < FIN; k++) acc = fmaf(xr[k], sW[k * FOUT + j], acc);
    Y[tid] = acc * dinv[i];
}

// out[i,f] = dinv[i] * (hs[i,f] + sum_{k in row i} hs[col[k], f]) + bias[f]
template<int F>
__global__ void agg_kernel(const float* __restrict__ hs, const int* __restrict__ rowptr,
                           const int* __restrict__ col, const float* __restrict__ dinv,
                           const float* __restrict__ bias, float* __restrict__ out, int n) {
    int tid = blockIdx.x * blockDim.x + threadIdx.x;
    if (tid >= n * F) return;
    int i = tid / F;
    int f = tid - i * F;
    int s = rowptr[i], e = rowptr[i + 1];
    float acc = hs[tid];
    for (int k = s; k < e; k++) {
        int c = col[k];
        acc += hs[(size_t)c * F + f];
    }
    out[tid] = acc * dinv[i] + bias[f];
}

// out = sigmoid([h2(96) | xl(40) | dw(64)] @ Wf(200x40) + bf)
__global__ void fuse_kernel(const float* __restrict__ h2, const float* __restrict__ xl,
                            const float* __restrict__ dwk, const float* __restrict__ Wf,
                            const float* __restrict__ bf, float* __restrict__ out, int n) {
    __shared__ float sW[200 * 40];
    for (int idx = threadIdx.x; idx < 200 * 40; idx += blockDim.x) sW[idx] = Wf[idx];
    __syncthreads();
    int tid = blockIdx.x * blockDim.x + threadIdx.x;
    if (tid >= n * 40) return;
    int i = tid / 40;
    int j = tid - i * 40;
    float acc = bf[j];
    const float* a = h2 + (size_t)i * 96;
#pragma unroll
    for (int k = 0; k < 96; k++) acc = fmaf(a[k], sW[k * 40 + j], acc);
    const float* b = xl + (size_t)i * 40;
#pragma unroll
    for (int k = 0; k < 40; k++) acc = fmaf(b[k], sW[(96 + k) * 40 + j], acc);
    const float* c = dwk + (size_t)i * 64;
#pragma unroll
    for (int k = 0; k < 64; k++) acc = fmaf(c[k], sW[(136 + k) * 40 + j], acc);
    out[tid] = 1.0f / (1.0f + expf(-acc));
}

extern "C" void kernel_launch(void* const* d_in, const int* in_sizes, int n_in,
                              void* d_out, int out_size, void* d_ws, size_t ws_size,
                              hipStream_t stream) {
    const float* x   = (const float*)d_in[0];
    const float* y   = (const float*)d_in[1];
    const int*   ei  = (const int*)d_in[2];
    const float* dwe = (const float*)d_in[3];
    const float* W1  = (const float*)d_in[4];
    const float* b1  = (const float*)d_in[5];
    const float* W2  = (const float*)d_in[6];
    const float* b2  = (const float*)d_in[7];
    const float* Wl  = (const float*)d_in[8];
    const float* bl  = (const float*)d_in[9];
    const float* Wf  = (const float*)d_in[10];
    const float* bf  = (const float*)d_in[11];
    float* out = (float*)d_out;

    const int n = in_sizes[0] / 128;
    const int E = in_sizes[2] / 2;
    const int* srcp = ei;
    const int* dstp = ei + E;

    char* ws = (char*)d_ws;
    size_t off = 0;
    auto alloc = [&](size_t bytes) -> void* {
        void* p = ws + off;
        off += bytes;
        off = (off + 255) & ~(size_t)255;
        return p;
    };

    int*   cnt    = (int*)alloc((size_t)n * 4);
    float* dinv   = (float*)alloc((size_t)n * 4);
    int*   rowptr = (int*)alloc((size_t)(n + 1) * 4);
    int*   cursor = (int*)alloc((size_t)n * 4);
    int*   col    = (int*)alloc((size_t)E * 4);
    float* A      = (float*)alloc((size_t)n * 96 * 4);   // matmul out (scaled)
    float* B      = (float*)alloc((size_t)n * 96 * 4);   // agg out
    float* L1     = (float*)alloc((size_t)n * 40 * 4);
    float* L2     = (float*)alloc((size_t)n * 40 * 4);
    (void)ws_size;

    const int gb_n  = (n + THREADS - 1) / THREADS;
    const int gb_e  = (E + THREADS - 1) / THREADS;
    const int gb_96 = (n * 96 + THREADS - 1) / THREADS;
    const int gb_40 = (n * 40 + THREADS - 1) / THREADS;

    // ---- build CSR (by dst) + dinv ----
    zero_i32<<<gb_n, THREADS, 0, stream>>>(cnt, n);
    count_kernel<<<gb_e, THREADS, 0, stream>>>(dstp, cnt, E);
    dinv_kernel<<<gb_n, THREADS, 0, stream>>>(cnt, dinv, n);
    scan_kernel<<<1, 1024, 0, stream>>>(cnt, rowptr, cursor, n);
    scatter_kernel<<<gb_e, THREADS, 0, stream>>>(srcp, dstp, cursor, col, E);

    // ---- feature propagation: 2 GCN layers ----
    mm_scale_kernel<128, 96><<<gb_96, THREADS, 0, stream>>>(x, W1, dinv, A, n);
    agg_kernel<96><<<gb_96, THREADS, 0, stream>>>(A, rowptr, col, dinv, b1, B, n);
    mm_scale_kernel<96, 96><<<gb_96, THREADS, 0, stream>>>(B, W2, dinv, A, n);
    agg_kernel<96><<<gb_96, THREADS, 0, stream>>>(A, rowptr, col, dinv, b2, B, n);

    // ---- label propagation: 10 GCN layers (ping-pong L1/L2, temp=A) ----
    const float* cur = y;
    for (int l = 0; l < 10; l++) {
        mm_scale_kernel<40, 40><<<gb_40, THREADS, 0, stream>>>(cur, Wl + (size_t)l * 40 * 40, dinv, A, n);
        float* nxt = (l & 1) ? L2 : L1;
        agg_kernel<40><<<gb_40, THREADS, 0, stream>>>(A, rowptr, col, dinv, bl + (size_t)l * 40, nxt, n);
        cur = nxt;
    }

    // ---- fuse + sigmoid ----
    fuse_kernel<<<gb_40, THREADS, 0, stream>>>(B, cur, dwe, Wf, bf, out, n);
}

// Round 2
// 879.681 us; speedup vs baseline: 1.8158x; 1.8158x over previous
//
#include <hip/hip_runtime.h>
#include <hip/hip_bf16.h>
#include <math.h>

#define THREADS 256

__global__ void zero_i32(int* __restrict__ p, int n) {
    int i = blockIdx.x * blockDim.x + threadIdx.x;
    if (i < n) p[i] = 0;
}

__global__ void count_kernel(const int* __restrict__ dst, int* __restrict__ cnt, int E) {
    int e = blockIdx.x * blockDim.x + threadIdx.x;
    if (e < E) atomicAdd(&cnt[dst[e]], 1);
}

__global__ void dinv_kernel(const int* __restrict__ cnt, float* __restrict__ dinv, int n) {
    int i = blockIdx.x * blockDim.x + threadIdx.x;
    if (i < n) dinv[i] = rsqrtf((float)cnt[i] + 1.0f);
}

// single-block exclusive scan over cnt -> rowptr[0..n], also copies to cursor
__global__ void scan_kernel(const int* __restrict__ cnt, int* __restrict__ rowptr,
                            int* __restrict__ cursor, int n) {
    __shared__ int smem[1024];
    __shared__ int s_running;
    if (threadIdx.x == 0) s_running = 0;
    __syncthreads();
    for (int base = 0; base < n; base += 1024) {
        int i = base + threadIdx.x;
        int v = (i < n) ? cnt[i] : 0;
        smem[threadIdx.x] = v;
        __syncthreads();
        int acc = v;
        for (int off = 1; off < 1024; off <<= 1) {
            int t = (threadIdx.x >= off) ? smem[threadIdx.x - off] : 0;
            __syncthreads();
            acc += t;
            smem[threadIdx.x] = acc;
            __syncthreads();
        }
        int run = s_running;                 // uniform read
        int excl = run + acc - v;
        if (i < n) { rowptr[i] = excl; cursor[i] = excl; }
        __syncthreads();
        if (threadIdx.x == 0) s_running = run + smem[1023];
        __syncthreads();
    }
    if (threadIdx.x == 0) rowptr[n] = s_running;
}

__global__ void scatter_kernel(const int* __restrict__ src, const int* __restrict__ dst,
                               int* __restrict__ cursor, int* __restrict__ col, int E) {
    int e = blockIdx.x * blockDim.x + threadIdx.x;
    if (e < E) {
        int d = dst[e];
        int p = atomicAdd(&cursor[d], 1);
        col[p] = src[e];
    }
}

// ---------------------------------------------------------------------------
// Register-tiled GEMM: Y[n x FOUT] = X[n x FIN] @ W[FIN x FOUT], epilogue:
//   EPI=0: Y = acc * dinv[i]           (pre-scaled for aggregation)
//   EPI=1: Y = acc + bias[j]           (fuse, first piece)
//   EPI=2: Y += acc                    (fuse, accumulate)
//   EPI=3: Y = sigmoid(Y + acc)        (fuse, last piece)
// Block: 256 threads; tile 64 rows x FOUT cols; micro-tile 4 x TN per thread.
// ---------------------------------------------------------------------------
template<int FIN, int FOUT, int EPI>
__global__ __launch_bounds__(256) void gemm_kernel(
    const float* __restrict__ X, const float* __restrict__ W,
    const float* __restrict__ dinv, const float* __restrict__ bias,
    float* __restrict__ Y, int n)
{
    constexpr int KC = (FIN % 32 == 0) ? 32 : FIN;   // 32, or 40 for FIN=40
    constexpr int NCHUNK = FIN / KC;
    constexpr int TN = (FOUT + 15) / 16;             // 6 (FOUT=96) or 3 (FOUT=40)
    constexpr int FOUTP = TN * 16;                   // 96 or 48
    constexpr int BM = 64;
    constexpr int KP = KC + 4;                       // padded LDS stride (multiple of 4)
    constexpr int K4 = KC / 4;

    __shared__ __align__(16) float sX[BM * KP];      // [row][kk]
    __shared__ __align__(16) float sW[FOUTP * KP];   // transposed: [j][kk]

    const int tid = threadIdx.x;
    const int tj = tid & 15;          // col thread 0..15
    const int ti = tid >> 4;          // row thread 0..15
    const int i0 = blockIdx.x * BM;

    float acc[4][TN];
#pragma unroll
    for (int m = 0; m < 4; ++m)
#pragma unroll
        for (int u = 0; u < TN; ++u) acc[m][u] = 0.f;

    for (int c = 0; c < NCHUNK; ++c) {
        const int k0 = c * KC;
        __syncthreads();
        // stage X tile (float4 loads, coalesced)
        for (int v = tid; v < BM * K4; v += 256) {
            int r = v / K4;
            int kk4 = v - r * K4;
            int gi = i0 + r;
            float4 val = (gi < n) ? *(const float4*)(X + (size_t)gi * FIN + k0 + kk4 * 4)
                                  : make_float4(0.f, 0.f, 0.f, 0.f);
            float* p = &sX[r * KP + kk4 * 4];
            p[0] = val.x; p[1] = val.y; p[2] = val.z; p[3] = val.w;
        }
        // stage W chunk transposed (coalesced global read, scattered LDS write)
        for (int v = tid; v < KC * FOUT; v += 256) {
            int kk = v / FOUT;
            int j = v - kk * FOUT;
            sW[j * KP + kk] = W[(size_t)(k0 + kk) * FOUT + j];
        }
        __syncthreads();
        // compute: 4-wide k steps, ds_read_b128
#pragma unroll
        for (int kk = 0; kk < KC; kk += 4) {
            float4 xv[4];
#pragma unroll
            for (int m = 0; m < 4; ++m)
                xv[m] = *(const float4*)&sX[(ti + 16 * m) * KP + kk];
#pragma unroll
            for (int u = 0; u < TN; ++u) {
                float4 wv = *(const float4*)&sW[(tj + 16 * u) * KP + kk];
#pragma unroll
                for (int m = 0; m < 4; ++m) {
                    acc[m][u] = fmaf(xv[m].x, wv.x, acc[m][u]);
                    acc[m][u] = fmaf(xv[m].y, wv.y, acc[m][u]);
                    acc[m][u] = fmaf(xv[m].z, wv.z, acc[m][u]);
                    acc[m][u] = fmaf(xv[m].w, wv.w, acc[m][u]);
                }
            }
        }
    }

    // epilogue
#pragma unroll
    for (int m = 0; m < 4; ++m) {
        int gi = i0 + ti + 16 * m;
        if (gi >= n) continue;
        float dv = (EPI == 0) ? dinv[gi] : 1.f;
#pragma unroll
        for (int u = 0; u < TN; ++u) {
            int j = tj + 16 * u;
            if (j >= FOUT) continue;
            size_t o = (size_t)gi * FOUT + j;
            if constexpr (EPI == 0)      Y[o] = acc[m][u] * dv;
            else if constexpr (EPI == 1) Y[o] = acc[m][u] + bias[j];
            else if constexpr (EPI == 2) Y[o] = Y[o] + acc[m][u];
            else {
                float t = Y[o] + acc[m][u];
                Y[o] = 1.f / (1.f + expf(-t));
            }
        }
    }
}

// out[i,f] = dinv[i] * (hs[i,f] + sum_{k in row i} hs[col[k], f]) + bias[f]
// float4 over features: thread = (node, feature-quad)
template<int F>
__global__ void agg_kernel(const float* __restrict__ hs, const int* __restrict__ rowptr,
                           const int* __restrict__ col, const float* __restrict__ dinv,
                           const float* __restrict__ bias, float* __restrict__ out, int n) {
    constexpr int F4 = F / 4;
    int tid = blockIdx.x * blockDim.x + threadIdx.x;
    if (tid >= n * F4) return;
    int i = tid / F4;
    int f = tid - i * F4;
    int s = rowptr[i], e = rowptr[i + 1];
    const float4* hs4 = (const float4*)hs;
    float4 a = hs4[(size_t)i * F4 + f];
    float ax = a.x, ay = a.y, az = a.z, aw = a.w;
    for (int k = s; k < e; k++) {
        int c = col[k];
        float4 v = hs4[(size_t)c * F4 + f];
        ax += v.x; ay += v.y; az += v.z; aw += v.w;
    }
    float dv = dinv[i];
    float4 b = ((const float4*)bias)[f];
    float4 r;
    r.x = ax * dv + b.x;
    r.y = ay * dv + b.y;
    r.z = az * dv + b.z;
    r.w = aw * dv + b.w;
    ((float4*)out)[(size_t)i * F4 + f] = r;
}

extern "C" void kernel_launch(void* const* d_in, const int* in_sizes, int n_in,
                              void* d_out, int out_size, void* d_ws, size_t ws_size,
                              hipStream_t stream) {
    const float* x   = (const float*)d_in[0];
    const float* y   = (const float*)d_in[1];
    const int*   ei  = (const int*)d_in[2];
    const float* dwe = (const float*)d_in[3];
    const float* W1  = (const float*)d_in[4];
    const float* b1  = (const float*)d_in[5];
    const float* W2  = (const float*)d_in[6];
    const float* b2  = (const float*)d_in[7];
    const float* Wl  = (const float*)d_in[8];
    const float* bl  = (const float*)d_in[9];
    const float* Wf  = (const float*)d_in[10];
    const float* bf  = (const float*)d_in[11];
    float* out = (float*)d_out;

    const int n = in_sizes[0] / 128;
    const int E = in_sizes[2] / 2;
    const int* srcp = ei;
    const int* dstp = ei + E;

    char* ws = (char*)d_ws;
    size_t off = 0;
    auto alloc = [&](size_t bytes) -> void* {
        void* p = ws + off;
        off += bytes;
        off = (off + 255) & ~(size_t)255;
        return p;
    };

    int*   cnt    = (int*)alloc((size_t)n * 4);
    float* dinv   = (float*)alloc((size_t)n * 4);
    int*   rowptr = (int*)alloc((size_t)(n + 1) * 4);
    int*   cursor = (int*)alloc((size_t)n * 4);
    int*   col    = (int*)alloc((size_t)E * 4);
    float* A      = (float*)alloc((size_t)n * 96 * 4);   // matmul out (scaled)
    float* B      = (float*)alloc((size_t)n * 96 * 4);   // agg out
    float* L1     = (float*)alloc((size_t)n * 40 * 4);
    float* L2     = (float*)alloc((size_t)n * 40 * 4);
    (void)ws_size;

    const int gb_n   = (n + THREADS - 1) / THREADS;
    const int gb_e   = (E + THREADS - 1) / THREADS;
    const int gb_gm  = (n + 63) / 64;                          // gemm blocks
    const int gb_a96 = (n * 24 + THREADS - 1) / THREADS;       // agg F=96 (float4)
    const int gb_a40 = (n * 10 + THREADS - 1) / THREADS;       // agg F=40 (float4)

    // ---- build CSR (by dst) + dinv ----
    zero_i32<<<gb_n, THREADS, 0, stream>>>(cnt, n);
    count_kernel<<<gb_e, THREADS, 0, stream>>>(dstp, cnt, E);
    dinv_kernel<<<gb_n, THREADS, 0, stream>>>(cnt, dinv, n);
    scan_kernel<<<1, 1024, 0, stream>>>(cnt, rowptr, cursor, n);
    scatter_kernel<<<gb_e, THREADS, 0, stream>>>(srcp, dstp, cursor, col, E);

    // ---- feature propagation: 2 GCN layers ----
    gemm_kernel<128, 96, 0><<<gb_gm, THREADS, 0, stream>>>(x, W1, dinv, nullptr, A, n);
    agg_kernel<96><<<gb_a96, THREADS, 0, stream>>>(A, rowptr, col, dinv, b1, B, n);
    gemm_kernel<96, 96, 0><<<gb_gm, THREADS, 0, stream>>>(B, W2, dinv, nullptr, A, n);
    agg_kernel<96><<<gb_a96, THREADS, 0, stream>>>(A, rowptr, col, dinv, b2, B, n);

    // ---- label propagation: 10 GCN layers (ping-pong L1/L2, temp=A) ----
    const float* cur = y;
    for (int l = 0; l < 10; l++) {
        gemm_kernel<40, 40, 0><<<gb_gm, THREADS, 0, stream>>>(cur, Wl + (size_t)l * 40 * 40, dinv, nullptr, A, n);
        float* nxt = (l & 1) ? L2 : L1;
        agg_kernel<40><<<gb_a40, THREADS, 0, stream>>>(A, rowptr, col, dinv, bl + (size_t)l * 40, nxt, n);
        cur = nxt;
    }

    // ---- fuse + sigmoid: out = sigmoid(h2@Wf[0:96] + xl@Wf[96:136] + dw@Wf[136:200] + bf)
    gemm_kernel<96, 40, 1><<<gb_gm, THREADS, 0, stream>>>(B, Wf, nullptr, bf, out, n);
    gemm_kernel<40, 40, 2><<<gb_gm, THREADS, 0, stream>>>(cur, Wf + 96 * 40, nullptr, nullptr, out, n);
    gemm_kernel<64, 40, 3><<<gb_gm, THREADS, 0, stream>>>(dwe, Wf + 136 * 40, nullptr, nullptr, out, n);
}